// Round 1
// baseline (859.368 us; speedup 1.0000x reference)
//
#include <hip/hip_runtime.h>
#include <hip/hip_bf16.h>
#include <math.h>

#define N    50000
#define E    800000
#define NCT  32
#define EMB  256
#define HID  128
#define OUTD 512
#define NB_SCAN 49   // ceil(N/1024)

// ---------------------------------------------------------------------------
// k_init: ct[n] = argmax(onehot row), zero hist, softplus table for dispersion
// ---------------------------------------------------------------------------
__global__ void k_init(const float* __restrict__ onehot,
                       const float* __restrict__ dispersion,
                       int* __restrict__ ct, int* __restrict__ hist,
                       float* __restrict__ sp) {
    int i = blockIdx.x * 256 + threadIdx.x;
    if (i < N) {
        const float* row = onehot + (size_t)i * NCT;
        int c = 0;
        #pragma unroll
        for (int j = 0; j < NCT; j++)
            if (row[j] > 0.5f) c = j;
        ct[i] = c;
        hist[i] = 0;
    }
    if (i < OUTD * NCT) {
        float x = dispersion[i];
        // softplus(x) = log1p(exp(-|x|)) + max(x,0)
        sp[i] = log1pf(expf(-fabsf(x))) + fmaxf(x, 0.f);
    }
}

// ---------------------------------------------------------------------------
// k_xlr: per 32-node tile, regenerate x = elu(embed) in LDS, then
//        x_l = x@W_l + b_l and x_r = x@W_r + b_r. 128 threads (2 waves),
//        thread t owns output column t of BOTH W_l and W_r (8 FMA per b128).
// ---------------------------------------------------------------------------
__global__ __launch_bounds__(128) void k_xlr(
        const int* __restrict__ ct, const float* __restrict__ ldsc,
        const float* __restrict__ We, const float* __restrict__ be,
        const float* __restrict__ pWl, const float* __restrict__ pbl,
        const float* __restrict__ pWr, const float* __restrict__ pbr,
        float* __restrict__ xl, float* __restrict__ xr) {
    __shared__ float xs[32][EMB];
    __shared__ int   ctl[32];
    __shared__ float ldl[32];
    const int t  = threadIdx.x;
    const int n0 = blockIdx.x * 32;

    if (t < 32) {
        int n = n0 + t; if (n > N - 1) n = N - 1;
        ctl[t] = ct[n];
        ldl[t] = ldsc[n];
    }
    __syncthreads();

    // fill x tile (elu of gathered embed rows)
    const float w32a = We[NCT * EMB + t];
    const float w32b = We[NCT * EMB + 128 + t];
    const float ba   = be[t];
    const float bb   = be[128 + t];
    for (int m = 0; m < 32; m++) {
        const int c = ctl[m];
        const float l = ldl[m];
        float v0 = fmaf(l, w32a, We[c * EMB + t]) + ba;
        float v1 = fmaf(l, w32b, We[c * EMB + 128 + t]) + bb;
        xs[m][t]       = v0 > 0.f ? v0 : expm1f(v0);
        xs[m][128 + t] = v1 > 0.f ? v1 : expm1f(v1);
    }
    __syncthreads();

    float accl[32], accr[32];
    #pragma unroll
    for (int m = 0; m < 32; m++) { accl[m] = 0.f; accr[m] = 0.f; }

    for (int k = 0; k < EMB; k += 4) {
        const float l0 = pWl[(k + 0) * HID + t];
        const float l1 = pWl[(k + 1) * HID + t];
        const float l2 = pWl[(k + 2) * HID + t];
        const float l3 = pWl[(k + 3) * HID + t];
        const float r0 = pWr[(k + 0) * HID + t];
        const float r1 = pWr[(k + 1) * HID + t];
        const float r2 = pWr[(k + 2) * HID + t];
        const float r3 = pWr[(k + 3) * HID + t];
        #pragma unroll
        for (int m = 0; m < 32; m++) {
            float4 a = *reinterpret_cast<const float4*>(&xs[m][k]); // broadcast read
            accl[m] = fmaf(a.x, l0, fmaf(a.y, l1, fmaf(a.z, l2, fmaf(a.w, l3, accl[m]))));
            accr[m] = fmaf(a.x, r0, fmaf(a.y, r1, fmaf(a.z, r2, fmaf(a.w, r3, accr[m]))));
        }
    }

    const float bvl = pbl[t];
    const float bvr = pbr[t];
    for (int m = 0; m < 32; m++) {
        int n = n0 + m;
        if (n < N) {
            xl[(size_t)n * HID + t] = accl[m] + bvl;
            xr[(size_t)n * HID + t] = accr[m] + bvr;
        }
    }
}

// ---------------------------------------------------------------------------
// k_edge: 32 lanes per edge. logit[e] = att . leaky_relu(xl[src]+xr[dst]);
//         also histogram dst for CSR build.
// ---------------------------------------------------------------------------
__global__ __launch_bounds__(256) void k_edge(
        const int* __restrict__ eidx, const float* __restrict__ xl,
        const float* __restrict__ xr, const float* __restrict__ attv,
        float* __restrict__ logit, int* __restrict__ hist) {
    const int t = threadIdx.x;
    const int e = blockIdx.x * 8 + (t >> 5);
    if (e >= E) return;
    const int lane = t & 31;
    const int s = eidx[e];
    const int d = eidx[E + e];

    float4 a = reinterpret_cast<const float4*>(xl)[(size_t)s * (HID / 4) + lane];
    float4 b = reinterpret_cast<const float4*>(xr)[(size_t)d * (HID / 4) + lane];
    float4 v = make_float4(a.x + b.x, a.y + b.y, a.z + b.z, a.w + b.w);
    v.x = v.x > 0.f ? v.x : 0.2f * v.x;
    v.y = v.y > 0.f ? v.y : 0.2f * v.y;
    v.z = v.z > 0.f ? v.z : 0.2f * v.z;
    v.w = v.w > 0.f ? v.w : 0.2f * v.w;
    float4 w = reinterpret_cast<const float4*>(attv)[lane];
    float p = fmaf(v.x, w.x, fmaf(v.y, w.y, fmaf(v.z, w.z, v.w * w.w)));

    p += __shfl_xor(p, 16);
    p += __shfl_xor(p, 8);
    p += __shfl_xor(p, 4);
    p += __shfl_xor(p, 2);
    p += __shfl_xor(p, 1);

    if (lane == 0) {
        logit[e] = p;
        atomicAdd(&hist[d], 1);
    }
}

// ---------------------------------------------------------------------------
// 3-phase exclusive scan of hist[N] -> offs[N+1], cursor copy
// ---------------------------------------------------------------------------
__global__ __launch_bounds__(1024) void k_scan1(const int* __restrict__ hist,
                                                int* __restrict__ offs,
                                                int* __restrict__ bsum) {
    __shared__ int sb[2][1024];
    const int t = threadIdx.x;
    const int i = blockIdx.x * 1024 + t;
    int v = (i < N) ? hist[i] : 0;
    sb[0][t] = v;
    __syncthreads();
    int pin = 0;
    for (int off = 1; off < 1024; off <<= 1) {
        int x = sb[pin][t];
        if (t >= off) x += sb[pin][t - off];
        sb[pin ^ 1][t] = x;
        pin ^= 1;
        __syncthreads();
    }
    int incl = sb[pin][t];
    if (i < N) offs[i] = incl - v;           // local exclusive
    if (t == 1023) bsum[blockIdx.x] = incl;  // block total
}

__global__ void k_scan2(const int* __restrict__ bsum, int* __restrict__ bbase) {
    if (threadIdx.x == 0) {
        int run = 0;
        for (int j = 0; j < NB_SCAN; j++) { bbase[j] = run; run += bsum[j]; }
    }
}

__global__ __launch_bounds__(1024) void k_scan3(int* __restrict__ offs,
                                                int* __restrict__ cursor,
                                                const int* __restrict__ bbase) {
    const int t = threadIdx.x;
    const int i = blockIdx.x * 1024 + t;
    if (i < N) {
        int v = offs[i] + bbase[blockIdx.x];
        offs[i] = v;
        cursor[i] = v;
    }
    if (blockIdx.x == 0 && t == 0) offs[N] = E;
}

// ---------------------------------------------------------------------------
// k_scatter: CSR column list (edge ids grouped by dst)
// ---------------------------------------------------------------------------
__global__ __launch_bounds__(256) void k_scatter(const int* __restrict__ eidx,
                                                 int* __restrict__ cursor,
                                                 int* __restrict__ sorted) {
    const int e = blockIdx.x * 256 + threadIdx.x;
    if (e < E) {
        int d = eidx[E + e];
        int pos = atomicAdd(&cursor[d], 1);
        sorted[pos] = e;
    }
}

// ---------------------------------------------------------------------------
// k_agg: one 64-lane wave per node, 4 nodes per block. Softmax over incoming
//        edges (max via shuffle, denom accumulated uniformly), weighted sum
//        of xl[src] rows, then h = elu(agg + gat_bias). Zero atomics.
// ---------------------------------------------------------------------------
__global__ __launch_bounds__(256) void k_agg(
        const int* __restrict__ offs, const int* __restrict__ sorted,
        const float* __restrict__ logit, const int* __restrict__ eidx,
        const float* __restrict__ xl, const float* __restrict__ gb,
        float* __restrict__ hout) {
    const int t = threadIdx.x;
    const int n = blockIdx.x * 4 + (t >> 6);
    if (n >= N) return;
    const int lane = t & 63;
    const int s0  = offs[n];
    const int deg = offs[n + 1] - s0;

    float mx = -3.0e38f;
    for (int i = lane; i < deg; i += 64)
        mx = fmaxf(mx, logit[sorted[s0 + i]]);
    #pragma unroll
    for (int m = 32; m; m >>= 1)
        mx = fmaxf(mx, __shfl_xor(mx, m));

    float denom = 0.f, a0 = 0.f, a1 = 0.f;
    for (int i = 0; i < deg; i++) {
        int e = sorted[s0 + i];
        float w = expf(logit[e] - mx);   // uniform across wave
        denom += w;
        int src = eidx[e];
        a0 = fmaf(w, xl[(size_t)src * HID + lane], a0);
        a1 = fmaf(w, xl[(size_t)src * HID + 64 + lane], a1);
    }
    float inv = 1.f / (denom + 1e-16f);
    a0 = fmaf(a0, inv, gb[lane]);
    a1 = fmaf(a1, inv, gb[64 + lane]);
    hout[(size_t)n * HID + lane]      = a0 > 0.f ? a0 : expm1f(a0);
    hout[(size_t)n * HID + 64 + lane] = a1 > 0.f ? a1 : expm1f(a1);
}

// ---------------------------------------------------------------------------
// k_out: logits = h@W_out + b_out, disp = sp_table gather. 32-node tile,
//        256 threads, thread t owns columns t and t+256.
// ---------------------------------------------------------------------------
__global__ __launch_bounds__(256) void k_out(
        const float* __restrict__ h, const int* __restrict__ ct,
        const float* __restrict__ Wo, const float* __restrict__ bo,
        const float* __restrict__ sp, float* __restrict__ out) {
    __shared__ float hs[32][HID];
    const int t  = threadIdx.x;
    const int n0 = blockIdx.x * 32;

    int nvalid = N - n0; if (nvalid > 32) nvalid = 32;
    const int nf4 = nvalid * (HID / 4);
    const float4* src4 = reinterpret_cast<const float4*>(h + (size_t)n0 * HID);
    float4* hs4 = reinterpret_cast<float4*>(&hs[0][0]);
    #pragma unroll
    for (int r = 0; r < 4; r++) {
        int fi = t + r * 256;
        hs4[fi] = (fi < nf4) ? src4[fi] : make_float4(0.f, 0.f, 0.f, 0.f);
    }
    __syncthreads();

    float acc0[32], acc1[32];
    #pragma unroll
    for (int m = 0; m < 32; m++) { acc0[m] = 0.f; acc1[m] = 0.f; }

    const int c0 = t, c1 = t + 256;
    for (int k = 0; k < HID; k += 4) {
        const float b00 = Wo[(k + 0) * OUTD + c0];
        const float b01 = Wo[(k + 1) * OUTD + c0];
        const float b02 = Wo[(k + 2) * OUTD + c0];
        const float b03 = Wo[(k + 3) * OUTD + c0];
        const float b10 = Wo[(k + 0) * OUTD + c1];
        const float b11 = Wo[(k + 1) * OUTD + c1];
        const float b12 = Wo[(k + 2) * OUTD + c1];
        const float b13 = Wo[(k + 3) * OUTD + c1];
        #pragma unroll
        for (int m = 0; m < 32; m++) {
            float4 a = *reinterpret_cast<const float4*>(&hs[m][k]); // broadcast
            acc0[m] = fmaf(a.x, b00, fmaf(a.y, b01, fmaf(a.z, b02, fmaf(a.w, b03, acc0[m]))));
            acc1[m] = fmaf(a.x, b10, fmaf(a.y, b11, fmaf(a.z, b12, fmaf(a.w, b13, acc1[m]))));
        }
    }

    const float bv0 = bo[c0];
    const float bv1 = bo[c1];
    float* outd = out + (size_t)N * OUTD;
    for (int m = 0; m < nvalid; m++) {
        const int n = n0 + m;
        const int c = ct[n];
        out[(size_t)n * OUTD + c0]  = acc0[m] + bv0;
        out[(size_t)n * OUTD + c1]  = acc1[m] + bv1;
        outd[(size_t)n * OUTD + c0] = sp[c0 * NCT + c];
        outd[(size_t)n * OUTD + c1] = sp[c1 * NCT + c];
    }
}

// ---------------------------------------------------------------------------
extern "C" void kernel_launch(void* const* d_in, const int* in_sizes, int n_in,
                              void* d_out, int out_size, void* d_ws, size_t ws_size,
                              hipStream_t stream) {
    const float* onehot     = (const float*)d_in[0];
    const float* ldsc       = (const float*)d_in[1];
    const int*   eidx       = (const int*)  d_in[2];
    const float* We         = (const float*)d_in[3];
    const float* be         = (const float*)d_in[4];
    const float* Wl         = (const float*)d_in[5];
    const float* bl         = (const float*)d_in[6];
    const float* Wr         = (const float*)d_in[7];
    const float* br         = (const float*)d_in[8];
    const float* attv       = (const float*)d_in[9];
    const float* gb         = (const float*)d_in[10];
    const float* Wo         = (const float*)d_in[11];
    const float* bo         = (const float*)d_in[12];
    const float* dispersion = (const float*)d_in[13];

    float* ws     = (float*)d_ws;
    float* xl     = ws;                               // N*HID
    float* xr     = xl + (size_t)N * HID;             // N*HID (reused as h)
    float* logit  = xr + (size_t)N * HID;             // E
    int*   sorted = (int*)(logit + E);                // E
    int*   ct     = sorted + E;                       // N
    int*   offs   = ct + N;                           // N+1
    int*   cursor = offs + (N + 1);                   // N+1
    int*   hist   = cursor + (N + 1);                 // N
    float* sp     = (float*)(hist + N);               // OUTD*NCT
    int*   bsum   = (int*)(sp + OUTD * NCT);          // 64
    int*   bbase  = bsum + 64;                        // 64
    float* hbuf   = xr;                               // reuse xr after k_edge

    float* out = (float*)d_out;

    k_init<<<(N + 255) / 256, 256, 0, stream>>>(onehot, dispersion, ct, hist, sp);
    k_xlr<<<(N + 31) / 32, 128, 0, stream>>>(ct, ldsc, We, be, Wl, bl, Wr, br, xl, xr);
    k_edge<<<(E + 7) / 8, 256, 0, stream>>>(eidx, xl, xr, attv, logit, hist);
    k_scan1<<<NB_SCAN, 1024, 0, stream>>>(hist, offs, bsum);
    k_scan2<<<1, 64, 0, stream>>>(bsum, bbase);
    k_scan3<<<NB_SCAN, 1024, 0, stream>>>(offs, cursor, bbase);
    k_scatter<<<(E + 255) / 256, 256, 0, stream>>>(eidx, cursor, sorted);
    k_agg<<<(N + 3) / 4, 256, 0, stream>>>(offs, sorted, logit, eidx, xl, gb, hbuf);
    k_out<<<(N + 31) / 32, 256, 0, stream>>>(hbuf, ct, Wo, bo, sp, out);
}

// Round 2
// 673.899 us; speedup vs baseline: 1.2752x; 1.2752x over previous
//
#include <hip/hip_runtime.h>
#include <hip/hip_bf16.h>
#include <math.h>

#define N    50000
#define E    800000
#define NCT  32
#define EMB  256
#define HID  128
#define OUTD 512
#define NB_SCAN 49   // ceil(N/1024)
#define XPAD 257     // xs LDS stride (bank-conflict-free A reads)
#define HPAD 132     // hs LDS stride

__device__ __forceinline__ float4 fma4s(float a, float4 b, float4 c) {
    return make_float4(fmaf(a, b.x, c.x), fmaf(a, b.y, c.y),
                       fmaf(a, b.z, c.z), fmaf(a, b.w, c.w));
}
__device__ __forceinline__ float4 add4(float4 a, float4 b) {
    return make_float4(a.x + b.x, a.y + b.y, a.z + b.z, a.w + b.w);
}

// ---------------------------------------------------------------------------
// k_init: ct = argmax(onehot), hist = 0, softplus(dispersion) transposed
// ---------------------------------------------------------------------------
__global__ void k_init(const float* __restrict__ onehot,
                       const float* __restrict__ dispersion,
                       int* __restrict__ ct, int* __restrict__ hist,
                       float* __restrict__ spt) {
    int i = blockIdx.x * 256 + threadIdx.x;
    if (i < N) {
        const float* row = onehot + (size_t)i * NCT;
        int c = 0;
        #pragma unroll
        for (int j = 0; j < NCT; j++)
            if (row[j] > 0.5f) c = j;
        ct[i] = c;
        hist[i] = 0;
    }
    if (i < OUTD * NCT) {
        float x = dispersion[i];                 // [OUTD][NCT], i = c*32 + j
        float s = log1pf(expf(-fabsf(x))) + fmaxf(x, 0.f);
        int c = i >> 5, j = i & 31;
        spt[j * OUTD + c] = s;                   // transposed [NCT][OUTD]
    }
}

// ---------------------------------------------------------------------------
// k_hist: histogram of dst (int4 vectorized)
// ---------------------------------------------------------------------------
__global__ __launch_bounds__(256) void k_hist(const int* __restrict__ eidx,
                                              int* __restrict__ hist) {
    int i = blockIdx.x * 256 + threadIdx.x;
    if (i < E / 4) {
        int4 d = reinterpret_cast<const int4*>(eidx + E)[i];
        atomicAdd(&hist[d.x], 1);
        atomicAdd(&hist[d.y], 1);
        atomicAdd(&hist[d.z], 1);
        atomicAdd(&hist[d.w], 1);
    }
}

// ---------------------------------------------------------------------------
// k_xlr: regenerate x=elu(embed gather) in LDS, then [xl|xr] = x@[Wl|Wr]+b.
// 256 thr = 8 rowgrp(4 nodes) x 32 colgrp(8 cols). Conflict-free b32 A reads.
// ---------------------------------------------------------------------------
__global__ __launch_bounds__(256, 4) void k_xlr(
        const int* __restrict__ ct, const float* __restrict__ ldsc,
        const float* __restrict__ We, const float* __restrict__ be,
        const float* __restrict__ pWl, const float* __restrict__ pbl,
        const float* __restrict__ pWr, const float* __restrict__ pbr,
        float* __restrict__ xl, float* __restrict__ xr) {
    __shared__ float xs[32 * XPAD];
    __shared__ int   ctl[32];
    __shared__ float ldl[32];
    const int t  = threadIdx.x;
    const int n0 = blockIdx.x * 32;

    if (t < 32) {
        int n = n0 + t; if (n >= N) n = N - 1;
        ctl[t] = ct[n];
        ldl[t] = ldsc[n];
    }
    __syncthreads();

    {   // thread t owns embed dim t for all 32 nodes
        const float w32 = We[NCT * EMB + t];
        const float bb  = be[t];
        for (int m = 0; m < 32; m++) {
            float v = fmaf(ldl[m], w32, We[ctl[m] * EMB + t]) + bb;
            xs[m * XPAD + t] = v > 0.f ? v : expm1f(v);
        }
    }
    __syncthreads();

    const int cg = t & 31;
    const int rg = t >> 5;
    const int c  = cg * 8;                      // combined col 0..248
    const float* Wb = (c < HID) ? (pWl + c) : (pWr + (c - HID));
    const float* xrow = xs + rg * 4 * XPAD;

    float4 acc[4][2];
    #pragma unroll
    for (int r = 0; r < 4; r++) {
        acc[r][0] = make_float4(0.f, 0.f, 0.f, 0.f);
        acc[r][1] = make_float4(0.f, 0.f, 0.f, 0.f);
    }

    for (int k = 0; k < EMB; k += 4) {
        float4 b[4][2];
        #pragma unroll
        for (int kk = 0; kk < 4; kk++) {
            b[kk][0] = *reinterpret_cast<const float4*>(Wb + (k + kk) * HID);
            b[kk][1] = *reinterpret_cast<const float4*>(Wb + (k + kk) * HID + 4);
        }
        float a[4][4];
        #pragma unroll
        for (int kk = 0; kk < 4; kk++)
            #pragma unroll
            for (int r = 0; r < 4; r++)
                a[kk][r] = xrow[r * XPAD + k + kk];
        #pragma unroll
        for (int kk = 0; kk < 4; kk++)
            #pragma unroll
            for (int r = 0; r < 4; r++) {
                acc[r][0] = fma4s(a[kk][r], b[kk][0], acc[r][0]);
                acc[r][1] = fma4s(a[kk][r], b[kk][1], acc[r][1]);
            }
    }

    float* OutP;
    int cc;
    float4 bias0, bias1;
    if (c < HID) {
        OutP = xl; cc = c;
        bias0 = *reinterpret_cast<const float4*>(pbl + cc);
        bias1 = *reinterpret_cast<const float4*>(pbl + cc + 4);
    } else {
        OutP = xr; cc = c - HID;
        bias0 = *reinterpret_cast<const float4*>(pbr + cc);
        bias1 = *reinterpret_cast<const float4*>(pbr + cc + 4);
    }
    #pragma unroll
    for (int r = 0; r < 4; r++) {
        int n = n0 + rg * 4 + r;
        if (n < N) {
            *reinterpret_cast<float4*>(OutP + (size_t)n * HID + cc)     = add4(acc[r][0], bias0);
            *reinterpret_cast<float4*>(OutP + (size_t)n * HID + cc + 4) = add4(acc[r][1], bias1);
        }
    }
}

// ---------------------------------------------------------------------------
// 3-phase exclusive scan of hist[N] -> offs[N+1], cursor copy
// ---------------------------------------------------------------------------
__global__ __launch_bounds__(1024) void k_scan1(const int* __restrict__ hist,
                                                int* __restrict__ offs,
                                                int* __restrict__ bsum) {
    __shared__ int sb[2][1024];
    const int t = threadIdx.x;
    const int i = blockIdx.x * 1024 + t;
    int v = (i < N) ? hist[i] : 0;
    sb[0][t] = v;
    __syncthreads();
    int pin = 0;
    for (int off = 1; off < 1024; off <<= 1) {
        int x = sb[pin][t];
        if (t >= off) x += sb[pin][t - off];
        sb[pin ^ 1][t] = x;
        pin ^= 1;
        __syncthreads();
    }
    int incl = sb[pin][t];
    if (i < N) offs[i] = incl - v;
    if (t == 1023) bsum[blockIdx.x] = incl;
}

__global__ void k_scan2(const int* __restrict__ bsum, int* __restrict__ bbase) {
    if (threadIdx.x == 0) {
        int run = 0;
        for (int j = 0; j < NB_SCAN; j++) { bbase[j] = run; run += bsum[j]; }
    }
}

__global__ __launch_bounds__(1024) void k_scan3(int* __restrict__ offs,
                                                int* __restrict__ cursor,
                                                const int* __restrict__ bbase) {
    const int t = threadIdx.x;
    const int i = blockIdx.x * 1024 + t;
    if (i < N) {
        int v = offs[i] + bbase[blockIdx.x];
        offs[i] = v;
        cursor[i] = v;
    }
    if (blockIdx.x == 0 && t == 0) offs[N] = E;
}

// ---------------------------------------------------------------------------
// k_scatter: CSR adjacency storing SRC node id per slot (grouped by dst)
// ---------------------------------------------------------------------------
__global__ __launch_bounds__(256) void k_scatter(const int* __restrict__ eidx,
                                                 int* __restrict__ cursor,
                                                 int* __restrict__ sorted) {
    const int e = blockIdx.x * 256 + threadIdx.x;
    if (e < E) {
        int s = eidx[e];
        int d = eidx[E + e];
        int pos = atomicAdd(&cursor[d], 1);
        sorted[pos] = s;
    }
}

// ---------------------------------------------------------------------------
// k_agg: fused edge-logit + online scatter-softmax + weighted aggregation.
// One wave per dst node; each xl[src] row gathered ONCE (logit + accum).
// Writes h in place over xr (own row only -> race-free).
// ---------------------------------------------------------------------------
__global__ __launch_bounds__(256, 8) void k_agg(
        const int* __restrict__ offs, const int* __restrict__ srt,
        const float* __restrict__ xl, const float* __restrict__ attv,
        const float* __restrict__ gb, float* xrh) {
    const int t = threadIdx.x;
    const int n = blockIdx.x * 4 + (t >> 6);
    if (n >= N) return;
    const int lane = t & 63;
    const float2* xl2 = reinterpret_cast<const float2*>(xl);
    float2* xh2 = reinterpret_cast<float2*>(xrh);

    const float2 xr2 = xh2[(size_t)n * 64 + lane];
    const float2 at2 = reinterpret_cast<const float2*>(attv)[lane];
    const int i0  = offs[n];
    const int deg = offs[n + 1] - i0;

    float m = -3.0e38f, den = 0.f;
    float2 acc = make_float2(0.f, 0.f);
    float2 xnx = make_float2(0.f, 0.f);
    if (deg > 0) { int s = srt[i0]; xnx = xl2[(size_t)s * 64 + lane]; }

    for (int i = 0; i < deg; i++) {
        float2 xc = xnx;
        if (i + 1 < deg) { int s = srt[i0 + i + 1]; xnx = xl2[(size_t)s * 64 + lane]; }
        float vx = xc.x + xr2.x, vy = xc.y + xr2.y;
        vx = vx > 0.f ? vx : 0.2f * vx;
        vy = vy > 0.f ? vy : 0.2f * vy;
        float p = fmaf(vx, at2.x, vy * at2.y);
        #pragma unroll
        for (int msk = 32; msk; msk >>= 1) p += __shfl_xor(p, msk);
        if (p <= m) {
            float w = __expf(p - m);
            den += w;
            acc.x = fmaf(w, xc.x, acc.x);
            acc.y = fmaf(w, xc.y, acc.y);
        } else {                                  // wave-uniform branch
            float s = __expf(m - p);
            den = fmaf(den, s, 1.f);
            acc.x = fmaf(acc.x, s, xc.x);
            acc.y = fmaf(acc.y, s, xc.y);
            m = p;
        }
    }
    float inv = 1.f / (den + 1e-16f);
    const float2 g2 = reinterpret_cast<const float2*>(gb)[lane];
    float hx = fmaf(acc.x, inv, g2.x);
    float hy = fmaf(acc.y, inv, g2.y);
    hx = hx > 0.f ? hx : expm1f(hx);
    hy = hy > 0.f ? hy : expm1f(hy);
    xh2[(size_t)n * 64 + lane] = make_float2(hx, hy);
}

// ---------------------------------------------------------------------------
// k_out: logits = h@W_out + b_out; disp = spt gather. Same register tiling.
// ---------------------------------------------------------------------------
__global__ __launch_bounds__(256, 4) void k_out(
        const float* __restrict__ h, const int* __restrict__ ct,
        const float* __restrict__ Wo, const float* __restrict__ bo,
        const float* __restrict__ spt, float* __restrict__ out) {
    __shared__ float hs[32 * HPAD];
    __shared__ int ctl[32];
    const int t  = threadIdx.x;
    const int n0 = blockIdx.x * 32;

    if (t < 32) { int n = n0 + t; ctl[t] = ct[n < N ? n : N - 1]; }
    {
        const float4* h4 = reinterpret_cast<const float4*>(h);
        #pragma unroll
        for (int j = 0; j < 4; j++) {
            int idx4 = t + j * 256;          // 0..1023
            int row  = idx4 >> 5;            // 0..31
            int k4   = (idx4 & 31) * 4;
            int n = n0 + row;
            float4 v = (n < N) ? h4[(size_t)n * 32 + (idx4 & 31)]
                               : make_float4(0.f, 0.f, 0.f, 0.f);
            float* d = hs + row * HPAD + k4;
            d[0] = v.x; d[1] = v.y; d[2] = v.z; d[3] = v.w;
        }
    }
    __syncthreads();

    const int cg = t & 31, rg = t >> 5;
    const float* hrow = hs + rg * 4 * HPAD;
    float* outd = out + (size_t)N * OUTD;

    for (int cp = 0; cp < 2; cp++) {
        const int c = cp * 256 + cg * 8;
        float4 acc[4][2];
        #pragma unroll
        for (int r = 0; r < 4; r++) {
            acc[r][0] = make_float4(0.f, 0.f, 0.f, 0.f);
            acc[r][1] = make_float4(0.f, 0.f, 0.f, 0.f);
        }
        for (int k = 0; k < HID; k += 4) {
            float4 b[4][2];
            #pragma unroll
            for (int kk = 0; kk < 4; kk++) {
                b[kk][0] = *reinterpret_cast<const float4*>(Wo + (k + kk) * OUTD + c);
                b[kk][1] = *reinterpret_cast<const float4*>(Wo + (k + kk) * OUTD + c + 4);
            }
            float a[4][4];
            #pragma unroll
            for (int kk = 0; kk < 4; kk++)
                #pragma unroll
                for (int r = 0; r < 4; r++)
                    a[kk][r] = hrow[r * HPAD + k + kk];
            #pragma unroll
            for (int kk = 0; kk < 4; kk++)
                #pragma unroll
                for (int r = 0; r < 4; r++) {
                    acc[r][0] = fma4s(a[kk][r], b[kk][0], acc[r][0]);
                    acc[r][1] = fma4s(a[kk][r], b[kk][1], acc[r][1]);
                }
        }
        float4 bias0 = *reinterpret_cast<const float4*>(bo + c);
        float4 bias1 = *reinterpret_cast<const float4*>(bo + c + 4);
        #pragma unroll
        for (int r = 0; r < 4; r++) {
            int n = n0 + rg * 4 + r;
            if (n < N) {
                *reinterpret_cast<float4*>(out + (size_t)n * OUTD + c)     = add4(acc[r][0], bias0);
                *reinterpret_cast<float4*>(out + (size_t)n * OUTD + c + 4) = add4(acc[r][1], bias1);
                int cn = ctl[rg * 4 + r];
                float4 d0 = *reinterpret_cast<const float4*>(spt + cn * OUTD + c);
                float4 d1 = *reinterpret_cast<const float4*>(spt + cn * OUTD + c + 4);
                *reinterpret_cast<float4*>(outd + (size_t)n * OUTD + c)     = d0;
                *reinterpret_cast<float4*>(outd + (size_t)n * OUTD + c + 4) = d1;
            }
        }
    }
}

// ---------------------------------------------------------------------------
extern "C" void kernel_launch(void* const* d_in, const int* in_sizes, int n_in,
                              void* d_out, int out_size, void* d_ws, size_t ws_size,
                              hipStream_t stream) {
    const float* onehot     = (const float*)d_in[0];
    const float* ldsc       = (const float*)d_in[1];
    const int*   eidx       = (const int*)  d_in[2];
    const float* We         = (const float*)d_in[3];
    const float* be         = (const float*)d_in[4];
    const float* Wl         = (const float*)d_in[5];
    const float* bl         = (const float*)d_in[6];
    const float* Wr         = (const float*)d_in[7];
    const float* br         = (const float*)d_in[8];
    const float* attv       = (const float*)d_in[9];
    const float* gb         = (const float*)d_in[10];
    const float* Wo         = (const float*)d_in[11];
    const float* bo         = (const float*)d_in[12];
    const float* dispersion = (const float*)d_in[13];

    float* ws     = (float*)d_ws;
    float* xl     = ws;                               // N*HID
    float* xr     = xl + (size_t)N * HID;             // N*HID (h after k_agg)
    int*   sorted = (int*)(xr + (size_t)N * HID);     // E (src ids by dst)
    int*   ct     = sorted + E;                       // N
    int*   offs   = ct + N;                           // N+1
    int*   cursor = offs + (N + 1);                   // N+1
    int*   hist   = cursor + (N + 1);                 // N
    float* spt    = (float*)(hist + N);               // NCT*OUTD
    int*   bsum   = (int*)(spt + NCT * OUTD);         // 64
    int*   bbase  = bsum + 64;                        // 64

    float* out = (float*)d_out;

    k_init   <<<(N + 255) / 256, 256, 0, stream>>>(onehot, dispersion, ct, hist, spt);
    k_hist   <<<(E / 4 + 255) / 256, 256, 0, stream>>>(eidx, hist);
    k_xlr    <<<(N + 31) / 32, 256, 0, stream>>>(ct, ldsc, We, be, Wl, bl, Wr, br, xl, xr);
    k_scan1  <<<NB_SCAN, 1024, 0, stream>>>(hist, offs, bsum);
    k_scan2  <<<1, 64, 0, stream>>>(bsum, bbase);
    k_scan3  <<<NB_SCAN, 1024, 0, stream>>>(offs, cursor, bbase);
    k_scatter<<<(E + 255) / 256, 256, 0, stream>>>(eidx, cursor, sorted);
    k_agg    <<<(N + 3) / 4, 256, 0, stream>>>(offs, sorted, xl, attv, gb, xr);
    k_out    <<<(N + 31) / 32, 256, 0, stream>>>(xr, ct, Wo, bo, spt, out);
}

// Round 3
// 650.170 us; speedup vs baseline: 1.3218x; 1.0365x over previous
//
#include <hip/hip_runtime.h>
#include <hip/hip_bf16.h>
#include <math.h>

#define N    50000
#define E    800000
#define NCT  32
#define EMB  256
#define HID  128
#define OUTD 512
#define NB_SCAN 49   // ceil(N/1024)
#define XPAD 260     // xs LDS stride: mult of 4 (16B-aligned float4), broadcast reads
#define HPAD 132     // hs LDS stride: mult of 4

__device__ __forceinline__ float4 fma4s(float a, float4 b, float4 c) {
    return make_float4(fmaf(a, b.x, c.x), fmaf(a, b.y, c.y),
                       fmaf(a, b.z, c.z), fmaf(a, b.w, c.w));
}
__device__ __forceinline__ float4 add4(float4 a, float4 b) {
    return make_float4(a.x + b.x, a.y + b.y, a.z + b.z, a.w + b.w);
}

// ---------------------------------------------------------------------------
// k_init: ct = argmax(onehot), hist = 0, softplus(dispersion) transposed
// ---------------------------------------------------------------------------
__global__ void k_init(const float* __restrict__ onehot,
                       const float* __restrict__ dispersion,
                       int* __restrict__ ct, int* __restrict__ hist,
                       float* __restrict__ spt) {
    int i = blockIdx.x * 256 + threadIdx.x;
    if (i < N) {
        const float* row = onehot + (size_t)i * NCT;
        int c = 0;
        #pragma unroll
        for (int j = 0; j < NCT; j++)
            if (row[j] > 0.5f) c = j;
        ct[i] = c;
        hist[i] = 0;
    }
    if (i < OUTD * NCT) {
        float x = dispersion[i];                 // [OUTD][NCT], i = c*32 + j
        float s = log1pf(expf(-fabsf(x))) + fmaxf(x, 0.f);
        int c = i >> 5, j = i & 31;
        spt[j * OUTD + c] = s;                   // transposed [NCT][OUTD]
    }
}

// ---------------------------------------------------------------------------
// k_hist: histogram of dst (int4 vectorized)
// ---------------------------------------------------------------------------
__global__ __launch_bounds__(256) void k_hist(const int* __restrict__ eidx,
                                              int* __restrict__ hist) {
    int i = blockIdx.x * 256 + threadIdx.x;
    if (i < E / 4) {
        int4 d = reinterpret_cast<const int4*>(eidx + E)[i];
        atomicAdd(&hist[d.x], 1);
        atomicAdd(&hist[d.y], 1);
        atomicAdd(&hist[d.z], 1);
        atomicAdd(&hist[d.w], 1);
    }
}

// ---------------------------------------------------------------------------
// k_xlr: regenerate x=elu(embed gather) in LDS, then [xl|xr] = x@[Wl|Wr]+b.
// 256 thr = 8 rowgrp(4 nodes) x 32 colgrp(8 cols). ds_read_b128 A (broadcast).
// ---------------------------------------------------------------------------
__global__ __launch_bounds__(256, 4) void k_xlr(
        const int* __restrict__ ct, const float* __restrict__ ldsc,
        const float* __restrict__ We, const float* __restrict__ be,
        const float* __restrict__ pWl, const float* __restrict__ pbl,
        const float* __restrict__ pWr, const float* __restrict__ pbr,
        float* __restrict__ xl, float* __restrict__ xr) {
    __shared__ float xs[32 * XPAD];
    __shared__ int   ctl[32];
    __shared__ float ldl[32];
    const int t  = threadIdx.x;
    const int n0 = blockIdx.x * 32;

    if (t < 32) {
        int n = n0 + t; if (n >= N) n = N - 1;
        ctl[t] = ct[n];
        ldl[t] = ldsc[n];
    }
    __syncthreads();

    {   // thread t owns embed dim t for all 32 nodes
        const float w32 = We[NCT * EMB + t];
        const float bb  = be[t];
        for (int m = 0; m < 32; m++) {
            float v = fmaf(ldl[m], w32, We[ctl[m] * EMB + t]) + bb;
            xs[m * XPAD + t] = v > 0.f ? v : expm1f(v);
        }
    }
    __syncthreads();

    const int cg = t & 31;
    const int rg = t >> 5;
    const int c  = cg * 8;                      // combined col 0..248
    const float* Wb = (c < HID) ? (pWl + c) : (pWr + (c - HID));
    const float* xrow = xs + rg * 4 * XPAD;

    float4 acc[4][2];
    #pragma unroll
    for (int r = 0; r < 4; r++) {
        acc[r][0] = make_float4(0.f, 0.f, 0.f, 0.f);
        acc[r][1] = make_float4(0.f, 0.f, 0.f, 0.f);
    }

    for (int k = 0; k < EMB; k += 4) {
        float4 b[4][2];
        #pragma unroll
        for (int kk = 0; kk < 4; kk++) {
            b[kk][0] = *reinterpret_cast<const float4*>(Wb + (k + kk) * HID);
            b[kk][1] = *reinterpret_cast<const float4*>(Wb + (k + kk) * HID + 4);
        }
        float4 a[4];                             // a[r] spans kk 0..3
        #pragma unroll
        for (int r = 0; r < 4; r++)
            a[r] = *reinterpret_cast<const float4*>(xrow + r * XPAD + k);
        #pragma unroll
        for (int r = 0; r < 4; r++) {
            acc[r][0] = fma4s(a[r].x, b[0][0], acc[r][0]);
            acc[r][1] = fma4s(a[r].x, b[0][1], acc[r][1]);
            acc[r][0] = fma4s(a[r].y, b[1][0], acc[r][0]);
            acc[r][1] = fma4s(a[r].y, b[1][1], acc[r][1]);
            acc[r][0] = fma4s(a[r].z, b[2][0], acc[r][0]);
            acc[r][1] = fma4s(a[r].z, b[2][1], acc[r][1]);
            acc[r][0] = fma4s(a[r].w, b[3][0], acc[r][0]);
            acc[r][1] = fma4s(a[r].w, b[3][1], acc[r][1]);
        }
    }

    float* OutP;
    int cc;
    float4 bias0, bias1;
    if (c < HID) {
        OutP = xl; cc = c;
        bias0 = *reinterpret_cast<const float4*>(pbl + cc);
        bias1 = *reinterpret_cast<const float4*>(pbl + cc + 4);
    } else {
        OutP = xr; cc = c - HID;
        bias0 = *reinterpret_cast<const float4*>(pbr + cc);
        bias1 = *reinterpret_cast<const float4*>(pbr + cc + 4);
    }
    #pragma unroll
    for (int r = 0; r < 4; r++) {
        int n = n0 + rg * 4 + r;
        if (n < N) {
            *reinterpret_cast<float4*>(OutP + (size_t)n * HID + cc)     = add4(acc[r][0], bias0);
            *reinterpret_cast<float4*>(OutP + (size_t)n * HID + cc + 4) = add4(acc[r][1], bias1);
        }
    }
}

// ---------------------------------------------------------------------------
// 3-phase exclusive scan of hist[N] -> offs[N+1], cursor copy
// ---------------------------------------------------------------------------
__global__ __launch_bounds__(1024) void k_scan1(const int* __restrict__ hist,
                                                int* __restrict__ offs,
                                                int* __restrict__ bsum) {
    __shared__ int sb[2][1024];
    const int t = threadIdx.x;
    const int i = blockIdx.x * 1024 + t;
    int v = (i < N) ? hist[i] : 0;
    sb[0][t] = v;
    __syncthreads();
    int pin = 0;
    for (int off = 1; off < 1024; off <<= 1) {
        int x = sb[pin][t];
        if (t >= off) x += sb[pin][t - off];
        sb[pin ^ 1][t] = x;
        pin ^= 1;
        __syncthreads();
    }
    int incl = sb[pin][t];
    if (i < N) offs[i] = incl - v;
    if (t == 1023) bsum[blockIdx.x] = incl;
}

__global__ void k_scan2(const int* __restrict__ bsum, int* __restrict__ bbase) {
    if (threadIdx.x == 0) {
        int run = 0;
        for (int j = 0; j < NB_SCAN; j++) { bbase[j] = run; run += bsum[j]; }
    }
}

__global__ __launch_bounds__(1024) void k_scan3(int* __restrict__ offs,
                                                int* __restrict__ cursor,
                                                const int* __restrict__ bbase) {
    const int t = threadIdx.x;
    const int i = blockIdx.x * 1024 + t;
    if (i < N) {
        int v = offs[i] + bbase[blockIdx.x];
        offs[i] = v;
        cursor[i] = v;
    }
    if (blockIdx.x == 0 && t == 0) offs[N] = E;
}

// ---------------------------------------------------------------------------
// k_scatter: CSR adjacency storing SRC node id per slot (grouped by dst)
// ---------------------------------------------------------------------------
__global__ __launch_bounds__(256) void k_scatter(const int* __restrict__ eidx,
                                                 int* __restrict__ cursor,
                                                 int* __restrict__ sorted) {
    const int e = blockIdx.x * 256 + threadIdx.x;
    if (e < E) {
        int s = eidx[e];
        int d = eidx[E + e];
        int pos = atomicAdd(&cursor[d], 1);
        sorted[pos] = s;
    }
}

// ---------------------------------------------------------------------------
// k_agg: fused edge-logit + online scatter-softmax + weighted aggregation.
// One wave per dst node. 2-deep prefetch of xl[src] rows. Writes h over xr.
// ---------------------------------------------------------------------------
__global__ __launch_bounds__(256, 8) void k_agg(
        const int* __restrict__ offs, const int* __restrict__ srt,
        const float* __restrict__ xl, const float* __restrict__ attv,
        const float* __restrict__ gb, float* xrh) {
    const int t = threadIdx.x;
    const int n = blockIdx.x * 4 + (t >> 6);
    if (n >= N) return;
    const int lane = t & 63;
    const float2* xl2 = reinterpret_cast<const float2*>(xl);
    float2* xh2 = reinterpret_cast<float2*>(xrh);

    const float2 xr2 = xh2[(size_t)n * 64 + lane];
    const float2 at2 = reinterpret_cast<const float2*>(attv)[lane];
    const int i0  = offs[n];
    const int deg = offs[n + 1] - i0;

    float m = -3.0e38f, den = 0.f;
    float2 acc = make_float2(0.f, 0.f);
    float2 x0 = make_float2(0.f, 0.f), x1 = make_float2(0.f, 0.f);
    if (deg > 0) x0 = xl2[(size_t)srt[i0] * 64 + lane];
    if (deg > 1) x1 = xl2[(size_t)srt[i0 + 1] * 64 + lane];

    for (int i = 0; i < deg; i++) {
        float2 xc = x0;
        x0 = x1;
        if (i + 2 < deg) x1 = xl2[(size_t)srt[i0 + i + 2] * 64 + lane];
        float vx = xc.x + xr2.x, vy = xc.y + xr2.y;
        vx = fmaxf(vx, 0.f) + 0.2f * fminf(vx, 0.f);
        vy = fmaxf(vy, 0.f) + 0.2f * fminf(vy, 0.f);
        float p = fmaf(vx, at2.x, vy * at2.y);
        #pragma unroll
        for (int msk = 32; msk; msk >>= 1) p += __shfl_xor(p, msk);
        if (p <= m) {
            float w = __expf(p - m);
            den += w;
            acc.x = fmaf(w, xc.x, acc.x);
            acc.y = fmaf(w, xc.y, acc.y);
        } else {                                  // wave-uniform branch
            float s = __expf(m - p);
            den = fmaf(den, s, 1.f);
            acc.x = fmaf(acc.x, s, xc.x);
            acc.y = fmaf(acc.y, s, xc.y);
            m = p;
        }
    }
    float inv = 1.f / (den + 1e-16f);
    const float2 g2 = reinterpret_cast<const float2*>(gb)[lane];
    float hx = fmaf(acc.x, inv, g2.x);
    float hy = fmaf(acc.y, inv, g2.y);
    hx = hx > 0.f ? hx : expm1f(hx);
    hy = hy > 0.f ? hy : expm1f(hy);
    xh2[(size_t)n * 64 + lane] = make_float2(hx, hy);
}

// ---------------------------------------------------------------------------
// k_out: logits = h@W_out + b_out; disp = spt gather. ds_read_b128 A reads.
// ---------------------------------------------------------------------------
__global__ __launch_bounds__(256, 4) void k_out(
        const float* __restrict__ h, const int* __restrict__ ct,
        const float* __restrict__ Wo, const float* __restrict__ bo,
        const float* __restrict__ spt, float* __restrict__ out) {
    __shared__ float hs[32 * HPAD];
    __shared__ int ctl[32];
    const int t  = threadIdx.x;
    const int n0 = blockIdx.x * 32;

    if (t < 32) { int n = n0 + t; ctl[t] = ct[n < N ? n : N - 1]; }
    {
        const float4* h4 = reinterpret_cast<const float4*>(h);
        #pragma unroll
        for (int j = 0; j < 4; j++) {
            int idx4 = t + j * 256;          // 0..1023
            int row  = idx4 >> 5;            // 0..31
            int k4   = (idx4 & 31) * 4;
            int n = n0 + row;
            float4 v = (n < N) ? h4[(size_t)n * 32 + (idx4 & 31)]
                               : make_float4(0.f, 0.f, 0.f, 0.f);
            float* d = hs + row * HPAD + k4;
            d[0] = v.x; d[1] = v.y; d[2] = v.z; d[3] = v.w;
        }
    }
    __syncthreads();

    const int cg = t & 31, rg = t >> 5;
    const float* hrow = hs + rg * 4 * HPAD;
    float* outd = out + (size_t)N * OUTD;

    for (int cp = 0; cp < 2; cp++) {
        const int c = cp * 256 + cg * 8;
        float4 acc[4][2];
        #pragma unroll
        for (int r = 0; r < 4; r++) {
            acc[r][0] = make_float4(0.f, 0.f, 0.f, 0.f);
            acc[r][1] = make_float4(0.f, 0.f, 0.f, 0.f);
        }
        for (int k = 0; k < HID; k += 4) {
            float4 b[4][2];
            #pragma unroll
            for (int kk = 0; kk < 4; kk++) {
                b[kk][0] = *reinterpret_cast<const float4*>(Wo + (k + kk) * OUTD + c);
                b[kk][1] = *reinterpret_cast<const float4*>(Wo + (k + kk) * OUTD + c + 4);
            }
            float4 a[4];                         // a[r] spans kk 0..3
            #pragma unroll
            for (int r = 0; r < 4; r++)
                a[r] = *reinterpret_cast<const float4*>(hrow + r * HPAD + k);
            #pragma unroll
            for (int r = 0; r < 4; r++) {
                acc[r][0] = fma4s(a[r].x, b[0][0], acc[r][0]);
                acc[r][1] = fma4s(a[r].x, b[0][1], acc[r][1]);
                acc[r][0] = fma4s(a[r].y, b[1][0], acc[r][0]);
                acc[r][1] = fma4s(a[r].y, b[1][1], acc[r][1]);
                acc[r][0] = fma4s(a[r].z, b[2][0], acc[r][0]);
                acc[r][1] = fma4s(a[r].z, b[2][1], acc[r][1]);
                acc[r][0] = fma4s(a[r].w, b[3][0], acc[r][0]);
                acc[r][1] = fma4s(a[r].w, b[3][1], acc[r][1]);
            }
        }
        float4 bias0 = *reinterpret_cast<const float4*>(bo + c);
        float4 bias1 = *reinterpret_cast<const float4*>(bo + c + 4);
        #pragma unroll
        for (int r = 0; r < 4; r++) {
            int n = n0 + rg * 4 + r;
            if (n < N) {
                *reinterpret_cast<float4*>(out + (size_t)n * OUTD + c)     = add4(acc[r][0], bias0);
                *reinterpret_cast<float4*>(out + (size_t)n * OUTD + c + 4) = add4(acc[r][1], bias1);
                int cn = ctl[rg * 4 + r];
                float4 d0 = *reinterpret_cast<const float4*>(spt + cn * OUTD + c);
                float4 d1 = *reinterpret_cast<const float4*>(spt + cn * OUTD + c + 4);
                *reinterpret_cast<float4*>(outd + (size_t)n * OUTD + c)     = d0;
                *reinterpret_cast<float4*>(outd + (size_t)n * OUTD + c + 4) = d1;
            }
        }
    }
}

// ---------------------------------------------------------------------------
extern "C" void kernel_launch(void* const* d_in, const int* in_sizes, int n_in,
                              void* d_out, int out_size, void* d_ws, size_t ws_size,
                              hipStream_t stream) {
    const float* onehot     = (const float*)d_in[0];
    const float* ldsc       = (const float*)d_in[1];
    const int*   eidx       = (const int*)  d_in[2];
    const float* We         = (const float*)d_in[3];
    const float* be         = (const float*)d_in[4];
    const float* Wl         = (const float*)d_in[5];
    const float* bl         = (const float*)d_in[6];
    const float* Wr         = (const float*)d_in[7];
    const float* br         = (const float*)d_in[8];
    const float* attv       = (const float*)d_in[9];
    const float* gb         = (const float*)d_in[10];
    const float* Wo         = (const float*)d_in[11];
    const float* bo         = (const float*)d_in[12];
    const float* dispersion = (const float*)d_in[13];

    float* ws     = (float*)d_ws;
    float* xl     = ws;                               // N*HID
    float* xr     = xl + (size_t)N * HID;             // N*HID (h after k_agg)
    int*   sorted = (int*)(xr + (size_t)N * HID);     // E (src ids by dst)
    int*   ct     = sorted + E;                       // N
    int*   offs   = ct + N;                           // N+1
    int*   cursor = offs + (N + 1);                   // N+1
    int*   hist   = cursor + (N + 1);                 // N
    float* spt    = (float*)(hist + N);               // NCT*OUTD
    int*   bsum   = (int*)(spt + NCT * OUTD);         // 64
    int*   bbase  = bsum + 64;                        // 64

    float* out = (float*)d_out;

    k_init   <<<(N + 255) / 256, 256, 0, stream>>>(onehot, dispersion, ct, hist, spt);
    k_hist   <<<(E / 4 + 255) / 256, 256, 0, stream>>>(eidx, hist);
    k_xlr    <<<(N + 31) / 32, 256, 0, stream>>>(ct, ldsc, We, be, Wl, bl, Wr, br, xl, xr);
    k_scan1  <<<NB_SCAN, 1024, 0, stream>>>(hist, offs, bsum);
    k_scan2  <<<1, 64, 0, stream>>>(bsum, bbase);
    k_scan3  <<<NB_SCAN, 1024, 0, stream>>>(offs, cursor, bbase);
    k_scatter<<<(E + 255) / 256, 256, 0, stream>>>(eidx, cursor, sorted);
    k_agg    <<<(N + 3) / 4, 256, 0, stream>>>(offs, sorted, xl, attv, gb, xr);
    k_out    <<<(N + 31) / 32, 256, 0, stream>>>(xr, ct, Wo, bo, spt, out);
}

// Round 5
// 611.474 us; speedup vs baseline: 1.4054x; 1.0633x over previous
//
#include <hip/hip_runtime.h>
#include <hip/hip_bf16.h>
#include <math.h>

#define N    50000
#define E    800000
#define NCT  32
#define EMB  256
#define HID  128
#define OUTD 512
#define NB_SCAN 49   // ceil(N/1024)
#define XPAD 260     // xs LDS stride: mult of 4 (16B-aligned), broadcast reads
#define HPAD 132     // hs LDS stride: mult of 4

__device__ __forceinline__ float4 fma4s(float a, float4 b, float4 c) {
    return make_float4(fmaf(a, b.x, c.x), fmaf(a, b.y, c.y),
                       fmaf(a, b.z, c.z), fmaf(a, b.w, c.w));
}
__device__ __forceinline__ float4 add4(float4 a, float4 b) {
    return make_float4(a.x + b.x, a.y + b.y, a.z + b.z, a.w + b.w);
}

// ---------------------------------------------------------------------------
// k_init: ct = argmax(onehot), hist = 0, softplus(dispersion) transposed
// ---------------------------------------------------------------------------
__global__ void k_init(const float* __restrict__ onehot,
                       const float* __restrict__ dispersion,
                       int* __restrict__ ct, int* __restrict__ hist,
                       float* __restrict__ spt) {
    int i = blockIdx.x * 256 + threadIdx.x;
    if (i < N) {
        const float* row = onehot + (size_t)i * NCT;
        int c = 0;
        #pragma unroll
        for (int j = 0; j < NCT; j++)
            if (row[j] > 0.5f) c = j;
        ct[i] = c;
        hist[i] = 0;
    }
    if (i < OUTD * NCT) {
        float x = dispersion[i];                 // [OUTD][NCT], i = c*32 + j
        float s = log1pf(expf(-fabsf(x))) + fmaxf(x, 0.f);
        int c = i >> 5, j = i & 31;
        spt[j * OUTD + c] = s;                   // transposed [NCT][OUTD]
    }
}

// ---------------------------------------------------------------------------
// k_hist: histogram of dst (int4 vectorized)
// ---------------------------------------------------------------------------
__global__ __launch_bounds__(256) void k_hist(const int* __restrict__ eidx,
                                              int* __restrict__ hist) {
    int i = blockIdx.x * 256 + threadIdx.x;
    if (i < E / 4) {
        int4 d = reinterpret_cast<const int4*>(eidx + E)[i];
        atomicAdd(&hist[d.x], 1);
        atomicAdd(&hist[d.y], 1);
        atomicAdd(&hist[d.z], 1);
        atomicAdd(&hist[d.w], 1);
    }
}

// ---------------------------------------------------------------------------
// k_xlr: x=elu(embed gather) in LDS; [Wl|Wr] staged in LDS per 16-k chunk
// (loaded ONCE per block, shared by 4 waves -> 8x less VMEM traffic).
// Thread (cg,rg): rows rg*4..+3, Wl cols cg*4..+3 (accA), Wr cols cg*4..+3 (accB).
// B LDS reads: lane cg reads 16B at byte cg*16 -> stride-1 b128, conflict-free.
// ---------------------------------------------------------------------------
__global__ __launch_bounds__(256, 3) void k_xlr(
        const int* __restrict__ ct, const float* __restrict__ ldsc,
        const float* __restrict__ We, const float* __restrict__ be,
        const float* __restrict__ pWl, const float* __restrict__ pbl,
        const float* __restrict__ pWr, const float* __restrict__ pbr,
        float* __restrict__ xl, float* __restrict__ xr) {
    __shared__ float xs[32 * XPAD];
    __shared__ float Bs[16 * 256];   // [kk][256]: cols 0-127 Wl, 128-255 Wr
    __shared__ int   ctl[32];
    __shared__ float ldl[32];
    const int t  = threadIdx.x;
    const int n0 = blockIdx.x * 32;

    if (t < 32) {
        int n = n0 + t; if (n >= N) n = N - 1;
        ctl[t] = ct[n];
        ldl[t] = ldsc[n];
    }
    __syncthreads();

    {   // thread t owns embed dim t for all 32 nodes
        const float w32 = We[NCT * EMB + t];
        const float bb  = be[t];
        for (int m = 0; m < 32; m++) {
            float v = fmaf(ldl[m], w32, We[ctl[m] * EMB + t]) + bb;
            xs[m * XPAD + t] = v > 0.f ? v : expm1f(v);
        }
    }

    const int cg = t & 31;
    const int rg = t >> 5;
    const float* xrow = xs + rg * 4 * XPAD;
    const int cA = cg * 4;           // Wl col / combined col
    // staging map: fi = t + j*256 (j<4); kk = fi>>6, col = (fi&63)*4
    const int st_kk  = t >> 6;       // j adds 4 each step (256/64)
    const int st_col = (t & 63) * 4;

    float4 accA[4], accB[4];
    #pragma unroll
    for (int r = 0; r < 4; r++) {
        accA[r] = make_float4(0.f, 0.f, 0.f, 0.f);
        accB[r] = make_float4(0.f, 0.f, 0.f, 0.f);
    }

    for (int kc = 0; kc < EMB; kc += 16) {
        __syncthreads();             // prev chunk consumed
        #pragma unroll
        for (int j = 0; j < 4; j++) {
            int kk  = st_kk + j * 4;
            int col = st_col;
            const float* src = (col < HID) ? (pWl + (size_t)(kc + kk) * HID + col)
                                           : (pWr + (size_t)(kc + kk) * HID + col - HID);
            *reinterpret_cast<float4*>(&Bs[kk * 256 + col]) =
                *reinterpret_cast<const float4*>(src);
        }
        __syncthreads();

        #pragma unroll
        for (int kk = 0; kk < 16; kk += 4) {
            float4 bA[4], bB[4];
            #pragma unroll
            for (int q = 0; q < 4; q++) {
                bA[q] = *reinterpret_cast<const float4*>(&Bs[(kk + q) * 256 + cA]);
                bB[q] = *reinterpret_cast<const float4*>(&Bs[(kk + q) * 256 + 128 + cA]);
            }
            float4 a[4];
            #pragma unroll
            for (int r = 0; r < 4; r++)
                a[r] = *reinterpret_cast<const float4*>(xrow + r * XPAD + kc + kk);
            #pragma unroll
            for (int r = 0; r < 4; r++) {
                accA[r] = fma4s(a[r].x, bA[0], accA[r]);
                accB[r] = fma4s(a[r].x, bB[0], accB[r]);
                accA[r] = fma4s(a[r].y, bA[1], accA[r]);
                accB[r] = fma4s(a[r].y, bB[1], accB[r]);
                accA[r] = fma4s(a[r].z, bA[2], accA[r]);
                accB[r] = fma4s(a[r].z, bB[2], accB[r]);
                accA[r] = fma4s(a[r].w, bA[3], accA[r]);
                accB[r] = fma4s(a[r].w, bB[3], accB[r]);
            }
        }
    }

    const float4 biasA = *reinterpret_cast<const float4*>(pbl + cA);
    const float4 biasB = *reinterpret_cast<const float4*>(pbr + cA);
    #pragma unroll
    for (int r = 0; r < 4; r++) {
        int n = n0 + rg * 4 + r;
        if (n < N) {
            *reinterpret_cast<float4*>(xl + (size_t)n * HID + cA) = add4(accA[r], biasA);
            *reinterpret_cast<float4*>(xr + (size_t)n * HID + cA) = add4(accB[r], biasB);
        }
    }
}

// ---------------------------------------------------------------------------
// 3-phase exclusive scan of hist[N] -> offs[N+1], cursor copy
// ---------------------------------------------------------------------------
__global__ __launch_bounds__(1024) void k_scan1(const int* __restrict__ hist,
                                                int* __restrict__ offs,
                                                int* __restrict__ bsum) {
    __shared__ int sb[2][1024];
    const int t = threadIdx.x;
    const int i = blockIdx.x * 1024 + t;
    int v = (i < N) ? hist[i] : 0;
    sb[0][t] = v;
    __syncthreads();
    int pin = 0;
    for (int off = 1; off < 1024; off <<= 1) {
        int x = sb[pin][t];
        if (t >= off) x += sb[pin][t - off];
        sb[pin ^ 1][t] = x;
        pin ^= 1;
        __syncthreads();
    }
    int incl = sb[pin][t];
    if (i < N) offs[i] = incl - v;
    if (t == 1023) bsum[blockIdx.x] = incl;
}

__global__ void k_scan2(const int* __restrict__ bsum, int* __restrict__ bbase) {
    if (threadIdx.x == 0) {
        int run = 0;
        for (int j = 0; j < NB_SCAN; j++) { bbase[j] = run; run += bsum[j]; }
    }
}

__global__ __launch_bounds__(1024) void k_scan3(int* __restrict__ offs,
                                                int* __restrict__ cursor,
                                                const int* __restrict__ bbase) {
    const int t = threadIdx.x;
    const int i = blockIdx.x * 1024 + t;
    if (i < N) {
        int v = offs[i] + bbase[blockIdx.x];
        offs[i] = v;
        cursor[i] = v;
    }
    if (blockIdx.x == 0 && t == 0) offs[N] = E;
}

// ---------------------------------------------------------------------------
// k_scatter: CSR adjacency storing SRC node id per slot (grouped by dst)
// ---------------------------------------------------------------------------
__global__ __launch_bounds__(256) void k_scatter(const int* __restrict__ eidx,
                                                 int* __restrict__ cursor,
                                                 int* __restrict__ sorted) {
    const int e = blockIdx.x * 256 + threadIdx.x;
    if (e < E) {
        int s = eidx[e];
        int d = eidx[E + e];
        int pos = atomicAdd(&cursor[d], 1);
        sorted[pos] = s;
    }
}

// ---------------------------------------------------------------------------
// k_agg: fused edge-logit + online scatter-softmax + aggregation.
// 32 lanes per node (float4/lane), 2 nodes per wave, branchless online
// update, 4-deep row prefetch. Writes h over xr (own row only).
// ---------------------------------------------------------------------------
__global__ __launch_bounds__(256, 8) void k_agg(
        const int* __restrict__ offs, const int* __restrict__ srt,
        const float* __restrict__ xl, const float* __restrict__ attv,
        const float* __restrict__ gb, float* xrh) {
    const int t = threadIdx.x;
    const int n = blockIdx.x * 8 + (t >> 5);
    if (n >= N) return;
    const int lane = t & 31;
    const float4* xl4 = reinterpret_cast<const float4*>(xl);
    float4* xh4 = reinterpret_cast<float4*>(xrh);

    const float4 xr4 = xh4[(size_t)n * 32 + lane];
    const float4 at4 = reinterpret_cast<const float4*>(attv)[lane];
    const int i0  = offs[n];
    const int deg = offs[n + 1] - i0;

    float m = -3.0e38f, den = 0.f;
    float4 acc = make_float4(0.f, 0.f, 0.f, 0.f);

#define STEP(XC) {                                                          \
    float vx = XC.x + xr4.x, vy = XC.y + xr4.y,                             \
          vz = XC.z + xr4.z, vw = XC.w + xr4.w;                             \
    vx = fmaxf(vx, 0.f) + 0.2f * fminf(vx, 0.f);                            \
    vy = fmaxf(vy, 0.f) + 0.2f * fminf(vy, 0.f);                            \
    vz = fmaxf(vz, 0.f) + 0.2f * fminf(vz, 0.f);                            \
    vw = fmaxf(vw, 0.f) + 0.2f * fminf(vw, 0.f);                            \
    float p = fmaf(vx, at4.x, fmaf(vy, at4.y, fmaf(vz, at4.z, vw * at4.w)));\
    p += __shfl_xor(p, 16); p += __shfl_xor(p, 8);                          \
    p += __shfl_xor(p, 4);  p += __shfl_xor(p, 2); p += __shfl_xor(p, 1);   \
    float mn = fmaxf(m, p);                                                 \
    float sc = __expf(m - mn);                                              \
    float w  = __expf(p - mn);                                              \
    den   = fmaf(den, sc, w);                                               \
    acc.x = fmaf(acc.x, sc, w * XC.x);                                      \
    acc.y = fmaf(acc.y, sc, w * XC.y);                                      \
    acc.z = fmaf(acc.z, sc, w * XC.z);                                      \
    acc.w = fmaf(acc.w, sc, w * XC.w);                                      \
    m = mn; }

    if (deg > 0) {
        const int lastI = i0 + deg - 1;
        #define LDX(J) xl4[(size_t)srt[min(i0 + (J), lastI)] * 32 + lane]
        float4 x0 = LDX(0), x1 = LDX(1), x2 = LDX(2), x3 = LDX(3);
        int i = 0;
        for (; i + 4 <= deg; i += 4) {
            const int base = i0 + i + 4;
            float4 n0 = xl4[(size_t)srt[min(base + 0, lastI)] * 32 + lane];
            float4 n1 = xl4[(size_t)srt[min(base + 1, lastI)] * 32 + lane];
            float4 n2 = xl4[(size_t)srt[min(base + 2, lastI)] * 32 + lane];
            float4 n3 = xl4[(size_t)srt[min(base + 3, lastI)] * 32 + lane];
            STEP(x0); STEP(x1); STEP(x2); STEP(x3);
            x0 = n0; x1 = n1; x2 = n2; x3 = n3;
        }
        if (i     < deg) STEP(x0);
        if (i + 1 < deg) STEP(x1);
        if (i + 2 < deg) STEP(x2);
        #undef LDX
    }
#undef STEP

    float inv = 1.f / (den + 1e-16f);
    const float4 g4 = reinterpret_cast<const float4*>(gb)[lane];
    float hx = fmaf(acc.x, inv, g4.x);
    float hy = fmaf(acc.y, inv, g4.y);
    float hz = fmaf(acc.z, inv, g4.z);
    float hw = fmaf(acc.w, inv, g4.w);
    hx = hx > 0.f ? hx : expm1f(hx);
    hy = hy > 0.f ? hy : expm1f(hy);
    hz = hz > 0.f ? hz : expm1f(hz);
    hw = hw > 0.f ? hw : expm1f(hw);
    xh4[(size_t)n * 32 + lane] = make_float4(hx, hy, hz, hw);
}

// ---------------------------------------------------------------------------
// k_out: logits = h@W_out + b_out; disp = spt gather. Wo staged in LDS per
// 16-k chunk. Thread cols per cp: cp*256+cg*4 (accA) and cp*256+128+cg*4 (accB).
// ---------------------------------------------------------------------------
__global__ __launch_bounds__(256, 3) void k_out(
        const float* __restrict__ h, const int* __restrict__ ct,
        const float* __restrict__ Wo, const float* __restrict__ bo,
        const float* __restrict__ spt, float* __restrict__ out) {
    __shared__ float hs[32 * HPAD];
    __shared__ float Bs[16 * OUTD];  // 32 KB: [kk][512]
    __shared__ int ctl[32];
    const int t  = threadIdx.x;
    const int n0 = blockIdx.x * 32;

    if (t < 32) { int n = n0 + t; ctl[t] = ct[n < N ? n : N - 1]; }
    {
        const float4* h4 = reinterpret_cast<const float4*>(h);
        #pragma unroll
        for (int j = 0; j < 4; j++) {
            int idx4 = t + j * 256;          // 0..1023
            int row  = idx4 >> 5;            // 0..31
            int k4   = (idx4 & 31) * 4;
            int n = n0 + row;
            float4 v = (n < N) ? h4[(size_t)n * 32 + (idx4 & 31)]
                               : make_float4(0.f, 0.f, 0.f, 0.f);
            float* d = hs + row * HPAD + k4;
            d[0] = v.x; d[1] = v.y; d[2] = v.z; d[3] = v.w;
        }
    }

    const int cg = t & 31, rg = t >> 5;
    const float* hrow = hs + rg * 4 * HPAD;
    const int cA = cg * 4;
    // staging map: fi = t + j*256 (j<8); kk = fi>>7, col = (fi&127)*4
    const int st_kk  = t >> 7;       // j adds 2 each step
    const int st_col = (t & 127) * 4;

    float4 acc[2][4][2];             // [cp][r][A/B]
    #pragma unroll
    for (int cp = 0; cp < 2; cp++)
        #pragma unroll
        for (int r = 0; r < 4; r++) {
            acc[cp][r][0] = make_float4(0.f, 0.f, 0.f, 0.f);
            acc[cp][r][1] = make_float4(0.f, 0.f, 0.f, 0.f);
        }

    for (int kc = 0; kc < HID; kc += 16) {
        __syncthreads();
        #pragma unroll
        for (int j = 0; j < 8; j++) {
            int kk = st_kk + j * 2;
            *reinterpret_cast<float4*>(&Bs[kk * OUTD + st_col]) =
                *reinterpret_cast<const float4*>(Wo + (size_t)(kc + kk) * OUTD + st_col);
        }
        __syncthreads();

        #pragma unroll
        for (int kk = 0; kk < 16; kk += 4) {
            float4 a[4];
            #pragma unroll
            for (int r = 0; r < 4; r++)
                a[r] = *reinterpret_cast<const float4*>(hrow + r * HPAD + kc + kk);
            #pragma unroll
            for (int cp = 0; cp < 2; cp++) {
                float4 bA[4], bB[4];
                #pragma unroll
                for (int q = 0; q < 4; q++) {
                    bA[q] = *reinterpret_cast<const float4*>(&Bs[(kk + q) * OUTD + cp * 256 + cA]);
                    bB[q] = *reinterpret_cast<const float4*>(&Bs[(kk + q) * OUTD + cp * 256 + 128 + cA]);
                }
                #pragma unroll
                for (int r = 0; r < 4; r++) {
                    acc[cp][r][0] = fma4s(a[r].x, bA[0], acc[cp][r][0]);
                    acc[cp][r][1] = fma4s(a[r].x, bB[0], acc[cp][r][1]);
                    acc[cp][r][0] = fma4s(a[r].y, bA[1], acc[cp][r][0]);
                    acc[cp][r][1] = fma4s(a[r].y, bB[1], acc[cp][r][1]);
                    acc[cp][r][0] = fma4s(a[r].z, bA[2], acc[cp][r][0]);
                    acc[cp][r][1] = fma4s(a[r].z, bB[2], acc[cp][r][1]);
                    acc[cp][r][0] = fma4s(a[r].w, bA[3], acc[cp][r][0]);
                    acc[cp][r][1] = fma4s(a[r].w, bB[3], acc[cp][r][1]);
                }
            }
        }
    }

    float* outd = out + (size_t)N * OUTD;
    #pragma unroll
    for (int cp = 0; cp < 2; cp++) {
        const int c0 = cp * 256 + cA;
        const int c1 = cp * 256 + 128 + cA;
        const float4 bias0 = *reinterpret_cast<const float4*>(bo + c0);
        const float4 bias1 = *reinterpret_cast<const float4*>(bo + c1);
        #pragma unroll
        for (int r = 0; r < 4; r++) {
            int n = n0 + rg * 4 + r;
            if (n < N) {
                *reinterpret_cast<float4*>(out + (size_t)n * OUTD + c0) = add4(acc[cp][r][0], bias0);
                *reinterpret_cast<float4*>(out + (size_t)n * OUTD + c1) = add4(acc[cp][r][1], bias1);
                int cn = ctl[rg * 4 + r];
                *reinterpret_cast<float4*>(outd + (size_t)n * OUTD + c0) =
                    *reinterpret_cast<const float4*>(spt + cn * OUTD + c0);
                *reinterpret_cast<float4*>(outd + (size_t)n * OUTD + c1) =
                    *reinterpret_cast<const float4*>(spt + cn * OUTD + c1);
            }
        }
    }
}

// ---------------------------------------------------------------------------
extern "C" void kernel_launch(void* const* d_in, const int* in_sizes, int n_in,
                              void* d_out, int out_size, void* d_ws, size_t ws_size,
                              hipStream_t stream) {
    const float* onehot     = (const float*)d_in[0];
    const float* ldsc       = (const float*)d_in[1];
    const int*   eidx       = (const int*)  d_in[2];
    const float* We         = (const float*)d_in[3];
    const float* be         = (const float*)d_in[4];
    const float* Wl         = (const float*)d_in[5];
    const float* bl         = (const float*)d_in[6];
    const float* Wr         = (const float*)d_in[7];
    const float* br         = (const float*)d_in[8];
    const float* attv       = (const float*)d_in[9];
    const float* gb         = (const float*)d_in[10];
    const float* Wo         = (const float*)d_in[11];
    const float* bo         = (const float*)d_in[12];
    const float* dispersion = (const float*)d_in[13];

    float* ws     = (float*)d_ws;
    float* xl     = ws;                               // N*HID
    float* xr     = xl + (size_t)N * HID;             // N*HID (h after k_agg)
    int*   sorted = (int*)(xr + (size_t)N * HID);     // E (src ids by dst)
    int*   ct     = sorted + E;                       // N
    int*   offs   = ct + N;                           // N+1
    int*   cursor = offs + (N + 1);                   // N+1
    int*   hist   = cursor + (N + 1);                 // N
    float* spt    = (float*)(hist + N);               // NCT*OUTD
    int*   bsum   = (int*)(spt + NCT * OUTD);         // 64
    int*   bbase  = bsum + 64;                        // 64

    float* out = (float*)d_out;

    k_init   <<<(N + 255) / 256, 256, 0, stream>>>(onehot, dispersion, ct, hist, spt);
    k_hist   <<<(E / 4 + 255) / 256, 256, 0, stream>>>(eidx, hist);
    k_xlr    <<<(N + 31) / 32, 256, 0, stream>>>(ct, ldsc, We, be, Wl, bl, Wr, br, xl, xr);
    k_scan1  <<<NB_SCAN, 1024, 0, stream>>>(hist, offs, bsum);
    k_scan2  <<<1, 64, 0, stream>>>(bsum, bbase);
    k_scan3  <<<NB_SCAN, 1024, 0, stream>>>(offs, cursor, bbase);
    k_scatter<<<(E + 255) / 256, 256, 0, stream>>>(eidx, cursor, sorted);
    k_agg    <<<(N + 7) / 8, 256, 0, stream>>>(offs, sorted, xl, attv, gb, xr);
    k_out    <<<(N + 31) / 32, 256, 0, stream>>>(xr, ct, Wo, bo, spt, out);
}

// Round 6
// 578.375 us; speedup vs baseline: 1.4858x; 1.0572x over previous
//
#include <hip/hip_runtime.h>
#include <hip/hip_bf16.h>
#include <math.h>

#define N    50000
#define E    800000
#define NCT  32
#define EMB  256
#define HID  128
#define OUTD 512
#define NB_SCAN 49   // ceil(N/1024)
#define XPAD 260     // xs LDS stride (16B-aligned; A reads are wave-broadcast)

__device__ __forceinline__ float4 fma4s(float a, float4 b, float4 c) {
    return make_float4(fmaf(a, b.x, c.x), fmaf(a, b.y, c.y),
                       fmaf(a, b.z, c.z), fmaf(a, b.w, c.w));
}
__device__ __forceinline__ float4 add4(float4 a, float4 b) {
    return make_float4(a.x + b.x, a.y + b.y, a.z + b.z, a.w + b.w);
}

// ---------------------------------------------------------------------------
// k_init: ct = argmax(onehot), hist = 0, softplus(dispersion) transposed
// ---------------------------------------------------------------------------
__global__ void k_init(const float* __restrict__ onehot,
                       const float* __restrict__ dispersion,
                       int* __restrict__ ct, int* __restrict__ hist,
                       float* __restrict__ spt) {
    int i = blockIdx.x * 256 + threadIdx.x;
    if (i < N) {
        const float* row = onehot + (size_t)i * NCT;
        int c = 0;
        #pragma unroll
        for (int j = 0; j < NCT; j++)
            if (row[j] > 0.5f) c = j;
        ct[i] = c;
        hist[i] = 0;
    }
    if (i < OUTD * NCT) {
        float x = dispersion[i];                 // [OUTD][NCT], i = c*32 + j
        float s = log1pf(expf(-fabsf(x))) + fmaxf(x, 0.f);
        int c = i >> 5, j = i & 31;
        spt[j * OUTD + c] = s;                   // transposed [NCT][OUTD]
    }
}

// ---------------------------------------------------------------------------
// k_hist: histogram of dst (int4 vectorized)
// ---------------------------------------------------------------------------
__global__ __launch_bounds__(256) void k_hist(const int* __restrict__ eidx,
                                              int* __restrict__ hist) {
    int i = blockIdx.x * 256 + threadIdx.x;
    if (i < E / 4) {
        int4 d = reinterpret_cast<const int4*>(eidx + E)[i];
        atomicAdd(&hist[d.x], 1);
        atomicAdd(&hist[d.y], 1);
        atomicAdd(&hist[d.z], 1);
        atomicAdd(&hist[d.w], 1);
    }
}

// ---------------------------------------------------------------------------
// k_xlr v2: block = 64 rows x 128 cols (blockIdx&1 selects Wl->xl or Wr->xr).
// 256 thr = 8 rowgrp x 32 colgrp; thread = 8 rows x 4 cols -> per 16-k chunk:
// 16 B-reads vs 1024 FMA-cyc (LDS pipe at ~50% when FMA at 100%).
// x = elu(embed gather) regenerated in LDS per block.
// ---------------------------------------------------------------------------
__global__ __launch_bounds__(256, 2) void k_xlr(
        const int* __restrict__ ct, const float* __restrict__ ldsc,
        const float* __restrict__ We, const float* __restrict__ be,
        const float* __restrict__ pWl, const float* __restrict__ pbl,
        const float* __restrict__ pWr, const float* __restrict__ pbr,
        float* __restrict__ xl, float* __restrict__ xr) {
    __shared__ float xs[64 * XPAD];  // 66.6 KB
    __shared__ float Bs[16 * HID];   // 8 KB chunk of Wl or Wr
    __shared__ int   ctl[64];
    __shared__ float ldl[64];
    const int t    = threadIdx.x;
    const int b    = blockIdx.x & 1;          // 0: Wl->xl, 1: Wr->xr
    const int n0   = (blockIdx.x >> 1) * 64;

    if (t < 64) {
        int n = n0 + t; if (n >= N) n = N - 1;
        ctl[t] = ct[n];
        ldl[t] = ldsc[n];
    }
    __syncthreads();

    {   // thread t owns embed dim t for all 64 rows
        const float w32 = We[NCT * EMB + t];
        const float bb  = be[t];
        for (int m = 0; m < 64; m++) {
            float v = fmaf(ldl[m], w32, We[ctl[m] * EMB + t]) + bb;
            xs[m * XPAD + t] = v > 0.f ? v : expm1f(v);
        }
    }

    const float* W  = b ? pWr : pbl == pbr ? pWr : pWl;  // (avoid cmov on hot path)
    const float* Wp = b ? pWr : pWl;
    (void)W;
    const int rg = t >> 5;                    // 0..7 -> rows rg*8..+7
    const int cg = t & 31;                    // cols cg*4..+3
    const int c  = cg * 4;
    const float* xrow = xs + rg * 8 * XPAD;
    // staging map: fi = t, t+256; kk = fi>>5, col4 = (fi&31)*4
    const int st_kk  = t >> 5;
    const int st_col = (t & 31) * 4;

    float4 acc[8];
    #pragma unroll
    for (int r = 0; r < 8; r++) acc[r] = make_float4(0.f, 0.f, 0.f, 0.f);

    for (int kc = 0; kc < EMB; kc += 16) {
        __syncthreads();                      // xs ready / prev chunk consumed
        *reinterpret_cast<float4*>(&Bs[st_kk * HID + st_col]) =
            *reinterpret_cast<const float4*>(Wp + (size_t)(kc + st_kk) * HID + st_col);
        *reinterpret_cast<float4*>(&Bs[(st_kk + 8) * HID + st_col]) =
            *reinterpret_cast<const float4*>(Wp + (size_t)(kc + st_kk + 8) * HID + st_col);
        __syncthreads();

        #pragma unroll
        for (int kk = 0; kk < 16; kk += 4) {
            float4 bq[4];
            #pragma unroll
            for (int q = 0; q < 4; q++)
                bq[q] = *reinterpret_cast<const float4*>(&Bs[(kk + q) * HID + c]);
            float4 a[8];
            #pragma unroll
            for (int r = 0; r < 8; r++)
                a[r] = *reinterpret_cast<const float4*>(xrow + r * XPAD + kc + kk);
            #pragma unroll
            for (int r = 0; r < 8; r++) {
                acc[r] = fma4s(a[r].x, bq[0], acc[r]);
                acc[r] = fma4s(a[r].y, bq[1], acc[r]);
                acc[r] = fma4s(a[r].z, bq[2], acc[r]);
                acc[r] = fma4s(a[r].w, bq[3], acc[r]);
            }
        }
    }

    float* outP = b ? xr : xl;
    const float4 bias = *reinterpret_cast<const float4*>((b ? pbr : pbl) + c);
    #pragma unroll
    for (int r = 0; r < 8; r++) {
        int n = n0 + rg * 8 + r;
        if (n < N)
            *reinterpret_cast<float4*>(outP + (size_t)n * HID + c) = add4(acc[r], bias);
    }
}

// ---------------------------------------------------------------------------
// 3-phase exclusive scan of hist[N] -> offs[N+1], cursor copy
// ---------------------------------------------------------------------------
__global__ __launch_bounds__(1024) void k_scan1(const int* __restrict__ hist,
                                                int* __restrict__ offs,
                                                int* __restrict__ bsum) {
    __shared__ int sb[2][1024];
    const int t = threadIdx.x;
    const int i = blockIdx.x * 1024 + t;
    int v = (i < N) ? hist[i] : 0;
    sb[0][t] = v;
    __syncthreads();
    int pin = 0;
    for (int off = 1; off < 1024; off <<= 1) {
        int x = sb[pin][t];
        if (t >= off) x += sb[pin][t - off];
        sb[pin ^ 1][t] = x;
        pin ^= 1;
        __syncthreads();
    }
    int incl = sb[pin][t];
    if (i < N) offs[i] = incl - v;
    if (t == 1023) bsum[blockIdx.x] = incl;
}

__global__ void k_scan2(const int* __restrict__ bsum, int* __restrict__ bbase) {
    if (threadIdx.x == 0) {
        int run = 0;
        for (int j = 0; j < NB_SCAN; j++) { bbase[j] = run; run += bsum[j]; }
    }
}

__global__ __launch_bounds__(1024) void k_scan3(int* __restrict__ offs,
                                                int* __restrict__ cursor,
                                                const int* __restrict__ bbase) {
    const int t = threadIdx.x;
    const int i = blockIdx.x * 1024 + t;
    if (i < N) {
        int v = offs[i] + bbase[blockIdx.x];
        offs[i] = v;
        cursor[i] = v;
    }
    if (blockIdx.x == 0 && t == 0) offs[N] = E;
}

// ---------------------------------------------------------------------------
// k_scatter: CSR adjacency storing SRC node id per slot (grouped by dst)
// ---------------------------------------------------------------------------
__global__ __launch_bounds__(256) void k_scatter(const int* __restrict__ eidx,
                                                 int* __restrict__ cursor,
                                                 int* __restrict__ sorted) {
    const int e = blockIdx.x * 256 + threadIdx.x;
    if (e < E) {
        int s = eidx[e];
        int d = eidx[E + e];
        int pos = atomicAdd(&cursor[d], 1);
        sorted[pos] = s;
    }
}

// ---------------------------------------------------------------------------
// k_agg: fused edge-logit + online scatter-softmax + aggregation.
// 32 lanes per node (float4/lane), 2 nodes per wave, branchless online
// update, 4-deep row prefetch. Writes h over xr (own row only).
// ---------------------------------------------------------------------------
__global__ __launch_bounds__(256, 8) void k_agg(
        const int* __restrict__ offs, const int* __restrict__ srt,
        const float* __restrict__ xl, const float* __restrict__ attv,
        const float* __restrict__ gb, float* xrh) {
    const int t = threadIdx.x;
    const int n = blockIdx.x * 8 + (t >> 5);
    if (n >= N) return;
    const int lane = t & 31;
    const float4* xl4 = reinterpret_cast<const float4*>(xl);
    float4* xh4 = reinterpret_cast<float4*>(xrh);

    const float4 xr4 = xh4[(size_t)n * 32 + lane];
    const float4 at4 = reinterpret_cast<const float4*>(attv)[lane];
    const int i0  = offs[n];
    const int deg = offs[n + 1] - i0;

    float m = -3.0e38f, den = 0.f;
    float4 acc = make_float4(0.f, 0.f, 0.f, 0.f);

#define STEP(XC) {                                                          \
    float vx = XC.x + xr4.x, vy = XC.y + xr4.y,                             \
          vz = XC.z + xr4.z, vw = XC.w + xr4.w;                             \
    vx = fmaxf(vx, 0.f) + 0.2f * fminf(vx, 0.f);                            \
    vy = fmaxf(vy, 0.f) + 0.2f * fminf(vy, 0.f);                            \
    vz = fmaxf(vz, 0.f) + 0.2f * fminf(vz, 0.f);                            \
    vw = fmaxf(vw, 0.f) + 0.2f * fminf(vw, 0.f);                            \
    float p = fmaf(vx, at4.x, fmaf(vy, at4.y, fmaf(vz, at4.z, vw * at4.w)));\
    p += __shfl_xor(p, 16); p += __shfl_xor(p, 8);                          \
    p += __shfl_xor(p, 4);  p += __shfl_xor(p, 2); p += __shfl_xor(p, 1);   \
    float mn = fmaxf(m, p);                                                 \
    float sc = __expf(m - mn);                                              \
    float w  = __expf(p - mn);                                              \
    den   = fmaf(den, sc, w);                                               \
    acc.x = fmaf(acc.x, sc, w * XC.x);                                      \
    acc.y = fmaf(acc.y, sc, w * XC.y);                                      \
    acc.z = fmaf(acc.z, sc, w * XC.z);                                      \
    acc.w = fmaf(acc.w, sc, w * XC.w);                                      \
    m = mn; }

    if (deg > 0) {
        const int lastI = i0 + deg - 1;
        #define LDX(J) xl4[(size_t)srt[min(i0 + (J), lastI)] * 32 + lane]
        float4 x0 = LDX(0), x1 = LDX(1), x2 = LDX(2), x3 = LDX(3);
        int i = 0;
        for (; i + 4 <= deg; i += 4) {
            const int base = i0 + i + 4;
            float4 n0 = xl4[(size_t)srt[min(base + 0, lastI)] * 32 + lane];
            float4 n1 = xl4[(size_t)srt[min(base + 1, lastI)] * 32 + lane];
            float4 n2 = xl4[(size_t)srt[min(base + 2, lastI)] * 32 + lane];
            float4 n3 = xl4[(size_t)srt[min(base + 3, lastI)] * 32 + lane];
            STEP(x0); STEP(x1); STEP(x2); STEP(x3);
            x0 = n0; x1 = n1; x2 = n2; x3 = n3;
        }
        if (i     < deg) STEP(x0);
        if (i + 1 < deg) STEP(x1);
        if (i + 2 < deg) STEP(x2);
        #undef LDX
    }
#undef STEP

    float inv = 1.f / (den + 1e-16f);
    const float4 g4 = reinterpret_cast<const float4*>(gb)[lane];
    float hx = fmaf(acc.x, inv, g4.x);
    float hy = fmaf(acc.y, inv, g4.y);
    float hz = fmaf(acc.z, inv, g4.z);
    float hw = fmaf(acc.w, inv, g4.w);
    hx = hx > 0.f ? hx : expm1f(hx);
    hy = hy > 0.f ? hy : expm1f(hy);
    hz = hz > 0.f ? hz : expm1f(hz);
    hw = hw > 0.f ? hw : expm1f(hw);
    xh4[(size_t)n * 32 + lane] = make_float4(hx, hy, hz, hw);
}

// ---------------------------------------------------------------------------
// k_out v2: block = 32 rows x 512 cols; 256 thr = 4 rowgrp(=wave: perfect
// A broadcast) x 64 colgrp; thread = 8 rows x 8 cols (two col-halves).
// Per 16-k chunk: 32 B-reads vs 2048 FMA-cyc -> LDS pipe ~50%.
// ---------------------------------------------------------------------------
__global__ __launch_bounds__(256, 3) void k_out(
        const float* __restrict__ h, const int* __restrict__ ct,
        const float* __restrict__ Wo, const float* __restrict__ bo,
        const float* __restrict__ spt, float* __restrict__ out) {
    __shared__ float hs[32 * HID];   // 16 KB
    __shared__ float Bs[16 * OUTD];  // 32 KB
    __shared__ int ctl[32];
    const int t  = threadIdx.x;
    const int n0 = blockIdx.x * 32;

    if (t < 32) { int n = n0 + t; ctl[t] = ct[n < N ? n : N - 1]; }
    {
        const float4* h4 = reinterpret_cast<const float4*>(h);
        #pragma unroll
        for (int j = 0; j < 4; j++) {
            int fi  = t + j * 256;           // 0..1023
            int row = fi >> 5;               // 0..31
            int k4  = (fi & 31) * 4;
            int n = n0 + row;
            float4 v = (n < N) ? h4[(size_t)n * 32 + (fi & 31)]
                               : make_float4(0.f, 0.f, 0.f, 0.f);
            *reinterpret_cast<float4*>(&hs[row * HID + k4]) = v;
        }
    }

    const int rg = t >> 6;                   // wave id: rows rg*8..+7
    const int cg = t & 63;
    const int c0 = cg * 4;                   // col-half 0
    const int c1 = 256 + cg * 4;             // col-half 1
    const float* hrow = hs + rg * 8 * HID;
    // staging map: fi = t + j*256 (j<8); kk = fi>>7, col = (fi&127)*4
    const int st_kk  = t >> 7;
    const int st_col = (t & 127) * 4;

    float4 acc0[8], acc1[8];
    #pragma unroll
    for (int r = 0; r < 8; r++) {
        acc0[r] = make_float4(0.f, 0.f, 0.f, 0.f);
        acc1[r] = make_float4(0.f, 0.f, 0.f, 0.f);
    }

    for (int kc = 0; kc < HID; kc += 16) {
        __syncthreads();                     // hs ready / prev chunk consumed
        #pragma unroll
        for (int j = 0; j < 8; j++) {
            int kk = st_kk + j * 2;
            *reinterpret_cast<float4*>(&Bs[kk * OUTD + st_col]) =
                *reinterpret_cast<const float4*>(Wo + (size_t)(kc + kk) * OUTD + st_col);
        }
        __syncthreads();

        #pragma unroll
        for (int kk = 0; kk < 16; kk += 4) {
            float4 a[8];
            #pragma unroll
            for (int r = 0; r < 8; r++)
                a[r] = *reinterpret_cast<const float4*>(hrow + r * HID + kc + kk);
            #pragma unroll
            for (int q = 0; q < 4; q++) {
                float4 b0 = *reinterpret_cast<const float4*>(&Bs[(kk + q) * OUTD + c0]);
                float4 b1 = *reinterpret_cast<const float4*>(&Bs[(kk + q) * OUTD + c1]);
                const float* aq = reinterpret_cast<const float*>(a);
                #pragma unroll
                for (int r = 0; r < 8; r++) {
                    float av = aq[r * 4 + q];
                    acc0[r] = fma4s(av, b0, acc0[r]);
                    acc1[r] = fma4s(av, b1, acc1[r]);
                }
            }
        }
    }

    float* outd = out + (size_t)N * OUTD;
    const float4 bias0 = *reinterpret_cast<const float4*>(bo + c0);
    const float4 bias1 = *reinterpret_cast<const float4*>(bo + c1);
    #pragma unroll
    for (int r = 0; r < 8; r++) {
        int row = rg * 8 + r;
        int n = n0 + row;
        if (n < N) {
            *reinterpret_cast<float4*>(out + (size_t)n * OUTD + c0) = add4(acc0[r], bias0);
            *reinterpret_cast<float4*>(out + (size_t)n * OUTD + c1) = add4(acc1[r], bias1);
            int cn = ctl[row];
            *reinterpret_cast<float4*>(outd + (size_t)n * OUTD + c0) =
                *reinterpret_cast<const float4*>(spt + cn * OUTD + c0);
            *reinterpret_cast<float4*>(outd + (size_t)n * OUTD + c1) =
                *reinterpret_cast<const float4*>(spt + cn * OUTD + c1);
        }
    }
}

// ---------------------------------------------------------------------------
extern "C" void kernel_launch(void* const* d_in, const int* in_sizes, int n_in,
                              void* d_out, int out_size, void* d_ws, size_t ws_size,
                              hipStream_t stream) {
    const float* onehot     = (const float*)d_in[0];
    const float* ldsc       = (const float*)d_in[1];
    const int*   eidx       = (const int*)  d_in[2];
    const float* We         = (const float*)d_in[3];
    const float* be         = (const float*)d_in[4];
    const float* Wl         = (const float*)d_in[5];
    const float* bl         = (const float*)d_in[6];
    const float* Wr         = (const float*)d_in[7];
    const float* br         = (const float*)d_in[8];
    const float* attv       = (const float*)d_in[9];
    const float* gb         = (const float*)d_in[10];
    const float* Wo         = (const float*)d_in[11];
    const float* bo         = (const float*)d_in[12];
    const float* dispersion = (const float*)d_in[13];

    float* ws     = (float*)d_ws;
    float* xl     = ws;                               // N*HID
    float* xr     = xl + (size_t)N * HID;             // N*HID (h after k_agg)
    int*   sorted = (int*)(xr + (size_t)N * HID);     // E (src ids by dst)
    int*   ct     = sorted + E;                       // N
    int*   offs   = ct + N;                           // N+1
    int*   cursor = offs + (N + 1);                   // N+1
    int*   hist   = cursor + (N + 1);                 // N
    float* spt    = (float*)(hist + N);               // NCT*OUTD
    int*   bsum   = (int*)(spt + NCT * OUTD);         // 64
    int*   bbase  = bsum + 64;                        // 64

    float* out = (float*)d_out;

    const int xlr_tiles = (N + 63) / 64;              // 782

    k_init   <<<(N + 255) / 256, 256, 0, stream>>>(onehot, dispersion, ct, hist, spt);
    k_hist   <<<(E / 4 + 255) / 256, 256, 0, stream>>>(eidx, hist);
    k_xlr    <<<xlr_tiles * 2, 256, 0, stream>>>(ct, ldsc, We, be, Wl, bl, Wr, br, xl, xr);
    k_scan1  <<<NB_SCAN, 1024, 0, stream>>>(hist, offs, bsum);
    k_scan2  <<<1, 64, 0, stream>>>(bsum, bbase);
    k_scan3  <<<NB_SCAN, 1024, 0, stream>>>(offs, cursor, bbase);
    k_scatter<<<(E + 255) / 256, 256, 0, stream>>>(eidx, cursor, sorted);
    k_agg    <<<(N + 7) / 8, 256, 0, stream>>>(offs, sorted, xl, attv, gb, xr);
    k_out    <<<(N + 31) / 32, 256, 0, stream>>>(xr, ct, Wo, bo, spt, out);
}